// Round 1
// baseline (1129.377 us; speedup 1.0000x reference)
//
#include <hip/hip_runtime.h>
#include <math.h>

#define B_  4
#define V_  256
#define C1_ 64
#define C2_ 32
#define H0_ 128
#define H2_ 256

// ---------------------------------------------------------------------------
// EdgeConvE: one block per (b, i) node. 256 threads = 128 neurons x 2 subgroups,
// each subgroup handles 4 edges of an 8-edge chunk. Adjacency row compacted in
// LDS; non-adjacent edges are never computed (ReLU>=0 makes max-with-0-init
// exactly equal to the reference's -1e9 masking).
// ---------------------------------------------------------------------------
template <int CIN>
__global__ __launch_bounds__(256) void conv_k(
    const int* __restrict__ adj, const float* __restrict__ x,
    const float* __restrict__ e,
    const float* __restrict__ W1, const float* __restrict__ b1,
    const float* __restrict__ W2, const float* __restrict__ b2,
    float* __restrict__ out)
{
    const int bi  = blockIdx.x;        // b*V + i
    const int b   = bi >> 8;
    const int tid = threadIdx.x;
    const int n   = tid & 127;
    const int sub = tid >> 7;          // 0 or 1

    __shared__ __align__(16) float s_xi[CIN];
    __shared__ __align__(16) float s_in[8][CIN + C2_];   // [x_j - x_i | e_ij]
    __shared__ __align__(16) float s_h1[8][H0_];
    __shared__ float s_other[H0_];
    __shared__ int   s_list[V_];
    __shared__ int   s_cnt;

    if (tid == 0) s_cnt = 0;
    for (int k = tid; k < CIN; k += 256) s_xi[k] = x[bi * CIN + k];
    __syncthreads();
    {   // compact adjacency row (order irrelevant for max)
        if (adj[bi * V_ + tid] > 0) {
            int p = atomicAdd(&s_cnt, 1);
            s_list[p] = tid;
        }
    }
    __syncthreads();
    const int cnt = s_cnt;

    // precompute x_i contribution to layer 1 (rows 0..CIN-1) + bias
    float acc0 = b1[n];
    #pragma unroll 4
    for (int k = 0; k < CIN; k += 4) {
        float4 xv = *reinterpret_cast<const float4*>(&s_xi[k]);
        acc0 = fmaf(xv.x, W1[(k + 0) * H0_ + n], acc0);
        acc0 = fmaf(xv.y, W1[(k + 1) * H0_ + n], acc0);
        acc0 = fmaf(xv.z, W1[(k + 2) * H0_ + n], acc0);
        acc0 = fmaf(xv.w, W1[(k + 3) * H0_ + n], acc0);
    }
    const float bias2 = b2[n];
    float vmax = 0.0f;

    const int KE = CIN + C2_;                   // per-edge rows (diff + e)
    const float* __restrict__ W1e = W1 + CIN * H0_;

    for (int t0 = 0; t0 < cnt; t0 += 8) {
        // cooperative load of 8 edges' [diff | e] vectors
        for (int idx = tid; idx < 8 * KE; idx += 256) {
            int ed = idx / KE;
            int k  = idx - ed * KE;
            int t  = t0 + ed; if (t >= cnt) t = cnt - 1;   // pad = duplicate
            int j  = s_list[t];
            float v;
            if (k < CIN) v = x[(b * V_ + j) * CIN + k] - s_xi[k];
            else         v = e[(bi * V_ + j) * C2_ + (k - CIN)];
            s_in[ed][k] = v;
        }
        __syncthreads();

        // layer 1: 4 edges per thread, float4-broadcast inputs
        float a[4];
        #pragma unroll
        for (int q = 0; q < 4; ++q) a[q] = acc0;
        for (int k = 0; k < KE; k += 4) {
            float w0 = W1e[(k + 0) * H0_ + n];
            float w1 = W1e[(k + 1) * H0_ + n];
            float w2 = W1e[(k + 2) * H0_ + n];
            float w3 = W1e[(k + 3) * H0_ + n];
            #pragma unroll
            for (int q = 0; q < 4; ++q) {
                float4 v = *reinterpret_cast<const float4*>(&s_in[sub * 4 + q][k]);
                a[q] = fmaf(v.x, w0, a[q]);
                a[q] = fmaf(v.y, w1, a[q]);
                a[q] = fmaf(v.z, w2, a[q]);
                a[q] = fmaf(v.w, w3, a[q]);
            }
        }
        #pragma unroll
        for (int q = 0; q < 4; ++q)
            s_h1[sub * 4 + q][n] = fmaxf(a[q], 0.0f);
        __syncthreads();

        // layer 2
        #pragma unroll
        for (int q = 0; q < 4; ++q) a[q] = bias2;
        for (int k = 0; k < H0_; k += 4) {
            float w0 = W2[(k + 0) * H0_ + n];
            float w1 = W2[(k + 1) * H0_ + n];
            float w2 = W2[(k + 2) * H0_ + n];
            float w3 = W2[(k + 3) * H0_ + n];
            #pragma unroll
            for (int q = 0; q < 4; ++q) {
                float4 v = *reinterpret_cast<const float4*>(&s_h1[sub * 4 + q][k]);
                a[q] = fmaf(v.x, w0, a[q]);
                a[q] = fmaf(v.y, w1, a[q]);
                a[q] = fmaf(v.z, w2, a[q]);
                a[q] = fmaf(v.w, w3, a[q]);
            }
        }
        #pragma unroll
        for (int q = 0; q < 4; ++q) {
            int t = t0 + sub * 4 + q;
            if (t < cnt) vmax = fmaxf(vmax, fmaxf(a[q], 0.0f));
        }
        __syncthreads();
    }

    if (sub == 1) s_other[n] = vmax;
    __syncthreads();
    if (sub == 0)
        out[bi * H0_ + n] = fmaxf(vmax, s_other[n]);   // isolated node -> 0
}

// ---------------------------------------------------------------------------
// Pair scoring: block per (b,i); f[i*V+j] = [x2_j , x2_i]. x_i half of layer 1
// hoisted out of the j loop. 8 pairs per pass, thread = 1 of 256 H2 neurons.
// ---------------------------------------------------------------------------
__global__ __launch_bounds__(256) void pair_k(
    const float* __restrict__ x2,
    const float* __restrict__ W3, const float* __restrict__ b3,
    const float* __restrict__ Wo, const float* __restrict__ bo,
    float* __restrict__ out)
{
    const int bi   = blockIdx.x;
    const int b    = bi >> 8;
    const int tid  = threadIdx.x;     // neuron n in [0,256)
    const int wave = tid >> 6, lane = tid & 63;

    __shared__ __align__(16) float s_xi[H0_];
    __shared__ __align__(16) float s_xj[8][H0_];
    __shared__ float s_part[8][4];

    if (tid < H0_) s_xi[tid] = x2[bi * H0_ + tid];
    __syncthreads();

    // bias + x_i contribution (rows H0..2H0-1 of W3)
    float acc0 = b3[tid];
    #pragma unroll 4
    for (int k = 0; k < H0_; k += 4) {
        float4 xv = *reinterpret_cast<const float4*>(&s_xi[k]);
        acc0 = fmaf(xv.x, W3[(H0_ + k + 0) * H2_ + tid], acc0);
        acc0 = fmaf(xv.y, W3[(H0_ + k + 1) * H2_ + tid], acc0);
        acc0 = fmaf(xv.z, W3[(H0_ + k + 2) * H2_ + tid], acc0);
        acc0 = fmaf(xv.w, W3[(H0_ + k + 3) * H2_ + tid], acc0);
    }
    const float wo  = Wo[tid];
    const float bo0 = bo[0];

    for (int j0 = 0; j0 < V_; j0 += 8) {
        for (int idx = tid; idx < 8 * H0_; idx += 256) {
            int ed = idx >> 7, k = idx & 127;
            s_xj[ed][k] = x2[(b * V_ + j0 + ed) * H0_ + k];
        }
        __syncthreads();

        float a[8];
        #pragma unroll
        for (int q = 0; q < 8; ++q) a[q] = acc0;
        for (int k = 0; k < H0_; k += 4) {
            float w0 = W3[(k + 0) * H2_ + tid];
            float w1 = W3[(k + 1) * H2_ + tid];
            float w2 = W3[(k + 2) * H2_ + tid];
            float w3 = W3[(k + 3) * H2_ + tid];
            #pragma unroll
            for (int q = 0; q < 8; ++q) {
                float4 v = *reinterpret_cast<const float4*>(&s_xj[q][k]);
                a[q] = fmaf(v.x, w0, a[q]);
                a[q] = fmaf(v.y, w1, a[q]);
                a[q] = fmaf(v.z, w2, a[q]);
                a[q] = fmaf(v.w, w3, a[q]);
            }
        }
        // layer 2: h3 . out_W, reduced across the 256 neurons
        #pragma unroll
        for (int q = 0; q < 8; ++q) {
            float p = fmaxf(a[q], 0.0f) * wo;
            #pragma unroll
            for (int off = 32; off > 0; off >>= 1)
                p += __shfl_down(p, off, 64);
            if (lane == 0) s_part[q][wave] = p;
        }
        __syncthreads();
        if (tid < 8) {
            float z = s_part[tid][0] + s_part[tid][1] + s_part[tid][2] +
                      s_part[tid][3] + bo0;
            out[bi * V_ + j0 + tid] = 1.0f / (1.0f + expf(-z));
        }
        __syncthreads();
    }
}

// ---------------------------------------------------------------------------
extern "C" void kernel_launch(void* const* d_in, const int* in_sizes, int n_in,
                              void* d_out, int out_size, void* d_ws, size_t ws_size,
                              hipStream_t stream) {
    const int*   adj   = (const int*)  d_in[0];
    const float* xf    = (const float*)d_in[1];
    const float* ea    = (const float*)d_in[2];
    const float* ec1W1 = (const float*)d_in[3];
    const float* ec1b1 = (const float*)d_in[4];
    const float* ec1W2 = (const float*)d_in[5];
    const float* ec1b2 = (const float*)d_in[6];
    const float* ec2W1 = (const float*)d_in[7];
    const float* ec2b1 = (const float*)d_in[8];
    const float* ec2W2 = (const float*)d_in[9];
    const float* ec2b2 = (const float*)d_in[10];
    const float* h3W   = (const float*)d_in[11];
    const float* h3b   = (const float*)d_in[12];
    const float* oW    = (const float*)d_in[13];
    const float* ob    = (const float*)d_in[14];
    float* out = (float*)d_out;

    float* x1 = (float*)d_ws;                 // (B,V,H0) fp32
    float* x2 = x1 + B_ * V_ * H0_;           // (B,V,H0) fp32

    conv_k<C1_><<<B_ * V_, 256, 0, stream>>>(adj, xf, ea, ec1W1, ec1b1, ec1W2, ec1b2, x1);
    conv_k<H0_><<<B_ * V_, 256, 0, stream>>>(adj, x1, ea, ec2W1, ec2b1, ec2W2, ec2b2, x2);
    pair_k<<<B_ * V_, 256, 0, stream>>>(x2, h3W, h3b, oW, ob, out);
}

// Round 2
// 411.815 us; speedup vs baseline: 2.7424x; 2.7424x over previous
//
#include <hip/hip_runtime.h>
#include <math.h>

#define B_  4
#define V_  256
#define C1_ 64
#define C2_ 32
#define H0_ 128
#define H2_ 256

// ---------------------------------------------------------------------------
// Per-node hoist for EdgeConvE layer 1:
//   h1(i,j) = relu( x_i@W1a + (x_j-x_i)@W1b + e_ij@W1c + b1 )
//           = relu( P[i] + Q[j] + e_ij@W1c )
//   P = x@(W1a-W1b) + b1 ,  Q = x@W1b
// One block per node, 128 threads (= output neuron n).
// ---------------------------------------------------------------------------
template <int CIN>
__global__ __launch_bounds__(128) void node_pre_k(
    const float* __restrict__ x, const float* __restrict__ W1,
    const float* __restrict__ b1, float* __restrict__ P, float* __restrict__ Q)
{
    const int bi = blockIdx.x, n = threadIdx.x;
    __shared__ __align__(16) float s_x[CIN];
    if (n < CIN) s_x[n] = x[bi * CIN + n];
    __syncthreads();
    float accP = b1[n], accQ = 0.f;
    #pragma unroll 4
    for (int k = 0; k < CIN; k += 4) {
        float4 xv = *reinterpret_cast<const float4*>(&s_x[k]);
        float wa0 = W1[(k + 0) * H0_ + n], wb0 = W1[(CIN + k + 0) * H0_ + n];
        float wa1 = W1[(k + 1) * H0_ + n], wb1 = W1[(CIN + k + 1) * H0_ + n];
        float wa2 = W1[(k + 2) * H0_ + n], wb2 = W1[(CIN + k + 2) * H0_ + n];
        float wa3 = W1[(k + 3) * H0_ + n], wb3 = W1[(CIN + k + 3) * H0_ + n];
        accP = fmaf(xv.x, wa0 - wb0, accP);  accQ = fmaf(xv.x, wb0, accQ);
        accP = fmaf(xv.y, wa1 - wb1, accP);  accQ = fmaf(xv.y, wb1, accQ);
        accP = fmaf(xv.z, wa2 - wb2, accP);  accQ = fmaf(xv.z, wb2, accQ);
        accP = fmaf(xv.w, wa3 - wb3, accP);  accQ = fmaf(xv.w, wb3, accQ);
    }
    P[bi * H0_ + n] = accP;
    Q[bi * H0_ + n] = accQ;
}

// ---------------------------------------------------------------------------
// EdgeConvE main: block per (b,i). 4 waves; each wave owns 8 edges per pass,
// each lane owns 2 neurons (n2, n2+64). Waves are fully independent in the
// K-loop (stage e themselves, produce and consume their own h1) -> no
// __syncthreads inside the loop. LDS reads are same-address broadcasts.
// Masked-max == max(0, max over adjacent j) since ReLU >= 0.
// ---------------------------------------------------------------------------
__global__ __launch_bounds__(256) void conv_main_k(
    const int* __restrict__ adj, const float* __restrict__ e,
    const float* __restrict__ P, const float* __restrict__ Q,
    const float* __restrict__ W1c, const float* __restrict__ W2,
    const float* __restrict__ b2, float* __restrict__ out)
{
    const int bi  = blockIdx.x;            // b*V + i
    const int b   = bi >> 8;
    const int tid = threadIdx.x;
    const int w   = tid >> 6;              // wave 0..3
    const int n2  = tid & 63;              // neurons n2 and n2+64

    __shared__ int   s_list[V_];
    __shared__ int   s_cnt;
    __shared__ __align__(16) float s_P[H0_];
    __shared__ __align__(16) float s_e[4][8][C2_];
    __shared__ __align__(16) float s_h1[4][8][H0_];
    __shared__ float s_m[4][H0_];

    if (tid == 0) s_cnt = 0;
    if (tid < H0_) s_P[tid] = P[bi * H0_ + tid];
    __syncthreads();
    if (adj[bi * V_ + tid] > 0) {          // compact adjacency row
        int p = atomicAdd(&s_cnt, 1);
        s_list[p] = tid;
    }
    __syncthreads();
    const int cnt = s_cnt;

    const float pa = s_P[n2], pb = s_P[n2 + 64];
    const float ba = b2[n2],  bb = b2[n2 + 64];
    float vmaxa = 0.f, vmaxb = 0.f;

    float (* __restrict__ se)[C2_] = s_e[w];
    float (* __restrict__ sh)[H0_] = s_h1[w];

    for (int t0 = w * 8; t0 < cnt; t0 += 32) {
        // stage this wave's 8 edges of e (lane -> one float4)
        {
            int q  = n2 >> 3;
            int kk = (n2 & 7) * 4;
            int t  = t0 + q; if (t >= cnt) t = cnt - 1;   // pad = duplicate
            int j  = s_list[t];
            *reinterpret_cast<float4*>(&se[q][kk]) =
                *reinterpret_cast<const float4*>(&e[(bi * V_ + j) * C2_ + kk]);
        }
        int jq[8];
        #pragma unroll
        for (int q = 0; q < 8; ++q) {
            int t = t0 + q; if (t >= cnt) t = cnt - 1;
            jq[q] = s_list[t];
        }

        // layer 1: acc = P[i] + Q[j] + e @ W1c
        float a0[8], a1[8];
        #pragma unroll
        for (int q = 0; q < 8; ++q) {
            const float* Qr = Q + (b * V_ + jq[q]) * H0_;
            a0[q] = pa + Qr[n2];
            a1[q] = pb + Qr[n2 + 64];
        }
        #pragma unroll
        for (int k = 0; k < C2_; k += 4) {
            float wa0 = W1c[(k + 0) * H0_ + n2], wb0 = W1c[(k + 0) * H0_ + n2 + 64];
            float wa1 = W1c[(k + 1) * H0_ + n2], wb1 = W1c[(k + 1) * H0_ + n2 + 64];
            float wa2 = W1c[(k + 2) * H0_ + n2], wb2 = W1c[(k + 2) * H0_ + n2 + 64];
            float wa3 = W1c[(k + 3) * H0_ + n2], wb3 = W1c[(k + 3) * H0_ + n2 + 64];
            #pragma unroll
            for (int q = 0; q < 8; ++q) {
                float4 v = *reinterpret_cast<const float4*>(&se[q][k]);
                a0[q] = fmaf(v.x, wa0, a0[q]); a1[q] = fmaf(v.x, wb0, a1[q]);
                a0[q] = fmaf(v.y, wa1, a0[q]); a1[q] = fmaf(v.y, wb1, a1[q]);
                a0[q] = fmaf(v.z, wa2, a0[q]); a1[q] = fmaf(v.z, wb2, a1[q]);
                a0[q] = fmaf(v.w, wa3, a0[q]); a1[q] = fmaf(v.w, wb3, a1[q]);
            }
        }
        #pragma unroll
        for (int q = 0; q < 8; ++q) {
            sh[q][n2]      = fmaxf(a0[q], 0.f);
            sh[q][n2 + 64] = fmaxf(a1[q], 0.f);
        }

        // layer 2: h2 = relu(h1 @ W2 + b2)
        #pragma unroll
        for (int q = 0; q < 8; ++q) { a0[q] = ba; a1[q] = bb; }
        #pragma unroll 4
        for (int k = 0; k < H0_; k += 4) {
            float wa0 = W2[(k + 0) * H0_ + n2], wb0 = W2[(k + 0) * H0_ + n2 + 64];
            float wa1 = W2[(k + 1) * H0_ + n2], wb1 = W2[(k + 1) * H0_ + n2 + 64];
            float wa2 = W2[(k + 2) * H0_ + n2], wb2 = W2[(k + 2) * H0_ + n2 + 64];
            float wa3 = W2[(k + 3) * H0_ + n2], wb3 = W2[(k + 3) * H0_ + n2 + 64];
            #pragma unroll
            for (int q = 0; q < 8; ++q) {
                float4 v = *reinterpret_cast<const float4*>(&sh[q][k]);
                a0[q] = fmaf(v.x, wa0, a0[q]); a1[q] = fmaf(v.x, wb0, a1[q]);
                a0[q] = fmaf(v.y, wa1, a0[q]); a1[q] = fmaf(v.y, wb1, a1[q]);
                a0[q] = fmaf(v.z, wa2, a0[q]); a1[q] = fmaf(v.z, wb2, a1[q]);
                a0[q] = fmaf(v.w, wa3, a0[q]); a1[q] = fmaf(v.w, wb3, a1[q]);
            }
        }
        #pragma unroll
        for (int q = 0; q < 8; ++q) {
            if (t0 + q < cnt) {
                vmaxa = fmaxf(vmaxa, fmaxf(a0[q], 0.f));
                vmaxb = fmaxf(vmaxb, fmaxf(a1[q], 0.f));
            }
        }
    }

    s_m[w][n2]      = vmaxa;
    s_m[w][n2 + 64] = vmaxb;
    __syncthreads();
    if (tid < H0_) {
        float m = fmaxf(fmaxf(s_m[0][tid], s_m[1][tid]),
                        fmaxf(s_m[2][tid], s_m[3][tid]));
        out[bi * H0_ + tid] = m;    // isolated node -> 0 (vmax init 0)
    }
}

// ---------------------------------------------------------------------------
// Pair hoist: f[i,j] = relu([x_j, x_i]@W3 + b3) = relu(Aj[j] + Ai[i]).
//   Aj = x2@W3[:H0], Ai = x2@W3[H0:] + b3. Block per node, thread = neuron.
// ---------------------------------------------------------------------------
__global__ __launch_bounds__(256) void pair_pre_k(
    const float* __restrict__ x2, const float* __restrict__ W3,
    const float* __restrict__ b3, float* __restrict__ Ai, float* __restrict__ Aj)
{
    const int bi = blockIdx.x, n = threadIdx.x;
    __shared__ __align__(16) float s_x[H0_];
    if (n < H0_) s_x[n] = x2[bi * H0_ + n];
    __syncthreads();
    float aI = b3[n], aJ = 0.f;
    #pragma unroll 4
    for (int k = 0; k < H0_; k += 4) {
        float4 xv = *reinterpret_cast<const float4*>(&s_x[k]);
        aJ = fmaf(xv.x, W3[(k + 0) * H2_ + n], aJ);
        aJ = fmaf(xv.y, W3[(k + 1) * H2_ + n], aJ);
        aJ = fmaf(xv.z, W3[(k + 2) * H2_ + n], aJ);
        aJ = fmaf(xv.w, W3[(k + 3) * H2_ + n], aJ);
        aI = fmaf(xv.x, W3[(H0_ + k + 0) * H2_ + n], aI);
        aI = fmaf(xv.y, W3[(H0_ + k + 1) * H2_ + n], aI);
        aI = fmaf(xv.z, W3[(H0_ + k + 2) * H2_ + n], aI);
        aI = fmaf(xv.w, W3[(H0_ + k + 3) * H2_ + n], aI);
    }
    Ai[bi * H2_ + n] = aI;
    Aj[bi * H2_ + n] = aJ;
}

// ---------------------------------------------------------------------------
// Pair output: block per (b,i); wave w handles j = w, w+4, ... Each lane owns
// 4 channels (float4). Full-wave shfl_xor reduce; no LDS, no block syncs.
// ---------------------------------------------------------------------------
__global__ __launch_bounds__(256) void pair_out_k(
    const float* __restrict__ Ai, const float* __restrict__ Aj,
    const float* __restrict__ Wo, const float* __restrict__ bo,
    float* __restrict__ out)
{
    const int bi   = blockIdx.x;
    const int b    = bi >> 8;
    const int w    = threadIdx.x >> 6;
    const int lane = threadIdx.x & 63;

    const float4 ai = *reinterpret_cast<const float4*>(&Ai[bi * H2_ + lane * 4]);
    const float4 wo = *reinterpret_cast<const float4*>(&Wo[lane * 4]);
    const float bo0 = bo[0];

    for (int j = w; j < V_; j += 4) {
        const float4 aj = *reinterpret_cast<const float4*>(&Aj[(b * V_ + j) * H2_ + lane * 4]);
        float p;
        p = fmaxf(ai.x + aj.x, 0.f) * wo.x;
        p = fmaf(fmaxf(ai.y + aj.y, 0.f), wo.y, p);
        p = fmaf(fmaxf(ai.z + aj.z, 0.f), wo.z, p);
        p = fmaf(fmaxf(ai.w + aj.w, 0.f), wo.w, p);
        #pragma unroll
        for (int off = 32; off > 0; off >>= 1)
            p += __shfl_xor(p, off, 64);
        if (lane == 0)
            out[bi * V_ + j] = 1.0f / (1.0f + __builtin_expf(-(p + bo0)));
    }
}

// ---------------------------------------------------------------------------
extern "C" void kernel_launch(void* const* d_in, const int* in_sizes, int n_in,
                              void* d_out, int out_size, void* d_ws, size_t ws_size,
                              hipStream_t stream) {
    const int*   adj   = (const int*)  d_in[0];
    const float* xf    = (const float*)d_in[1];
    const float* ea    = (const float*)d_in[2];
    const float* ec1W1 = (const float*)d_in[3];
    const float* ec1b1 = (const float*)d_in[4];
    const float* ec1W2 = (const float*)d_in[5];
    const float* ec1b2 = (const float*)d_in[6];
    const float* ec2W1 = (const float*)d_in[7];
    const float* ec2b1 = (const float*)d_in[8];
    const float* ec2W2 = (const float*)d_in[9];
    const float* ec2b2 = (const float*)d_in[10];
    const float* h3W   = (const float*)d_in[11];
    const float* h3b   = (const float*)d_in[12];
    const float* oW    = (const float*)d_in[13];
    const float* ob    = (const float*)d_in[14];
    float* out = (float*)d_out;

    const int NV = B_ * V_;                    // 1024 nodes
    float* x1 = (float*)d_ws;                  // NV*H0
    float* x2 = x1 + NV * H0_;                 // NV*H0
    float* R  = x2 + NV * H0_;                 // reuse region
    float* P  = R;                             // NV*H0
    float* Q  = R + NV * H0_;                  // NV*H0
    float* Ai = R;                             // NV*H2 (P/Q dead by then)
    float* Aj = R + NV * H2_;                  // NV*H2

    // conv1
    node_pre_k<C1_><<<NV, 128, 0, stream>>>(xf, ec1W1, ec1b1, P, Q);
    conv_main_k<<<NV, 256, 0, stream>>>(adj, ea, P, Q,
                                        ec1W1 + 2 * C1_ * H0_, ec1W2, ec1b2, x1);
    // conv2
    node_pre_k<H0_><<<NV, 128, 0, stream>>>(x1, ec2W1, ec2b1, P, Q);
    conv_main_k<<<NV, 256, 0, stream>>>(adj, ea, P, Q,
                                        ec2W1 + 2 * H0_ * H0_, ec2W2, ec2b2, x2);
    // pair scoring
    pair_pre_k<<<NV, 256, 0, stream>>>(x2, h3W, h3b, Ai, Aj);
    pair_out_k<<<NV, 256, 0, stream>>>(Ai, Aj, oW, ob, out);
}

// Round 3
// 236.441 us; speedup vs baseline: 4.7766x; 1.7417x over previous
//
#include <hip/hip_runtime.h>
#include <math.h>

#define B_  4
#define V_  256
#define C1_ 64
#define C2_ 32
#define H0_ 128
#define H2_ 256

typedef short bf16x8 __attribute__((ext_vector_type(8)));
typedef float f32x4  __attribute__((ext_vector_type(4)));

static __device__ __forceinline__ short f2bf(float f) {
    unsigned u = __float_as_uint(f);
    u += 0x7fffu + ((u >> 16) & 1u);          // RNE
    return (short)(u >> 16);
}

// ---------------------------------------------------------------------------
// Weight prep (runs every launch): transpose + bf16-convert the edge-part of
// W1 (W1c: [32][H0] -> [H0][32]) and W2 ([H0][H0] -> [H0][H0]^T) for both
// conv layers, so MFMA B-fragments are contiguous 16 B loads.
// Layout in wsW (shorts): W1cT1[128*32] | W2T1[128*128] | W1cT2 | W2T2
// ---------------------------------------------------------------------------
__global__ __launch_bounds__(256) void prep_k(
    const float* __restrict__ W1c1, const float* __restrict__ W21,
    const float* __restrict__ W1c2, const float* __restrict__ W22,
    short* __restrict__ wsW)
{
    int idx = blockIdx.x * 256 + threadIdx.x;        // 40960 total
    if (idx < 4096) {
        int n = idx >> 5, k = idx & 31;
        wsW[idx] = f2bf(W1c1[k * H0_ + n]);
    } else if (idx < 20480) {
        int t = idx - 4096; int n = t >> 7, k = t & 127;
        wsW[idx] = f2bf(W21[k * H0_ + n]);
    } else if (idx < 24576) {
        int t = idx - 20480; int n = t >> 5, k = t & 31;
        wsW[idx] = f2bf(W1c2[k * H0_ + n]);
    } else if (idx < 40960) {
        int t = idx - 24576; int n = t >> 7, k = t & 127;
        wsW[idx] = f2bf(W22[k * H0_ + n]);
    }
}

// ---------------------------------------------------------------------------
// Per-node hoist: P = x@(W1a-W1b)+b1, Q = x@W1b (fp32, unchanged from R2)
// ---------------------------------------------------------------------------
template <int CIN>
__global__ __launch_bounds__(128) void node_pre_k(
    const float* __restrict__ x, const float* __restrict__ W1,
    const float* __restrict__ b1, float* __restrict__ P, float* __restrict__ Q)
{
    const int bi = blockIdx.x, n = threadIdx.x;
    __shared__ __align__(16) float s_x[CIN];
    if (n < CIN) s_x[n] = x[bi * CIN + n];
    __syncthreads();
    float accP = b1[n], accQ = 0.f;
    #pragma unroll 4
    for (int k = 0; k < CIN; k += 4) {
        float4 xv = *reinterpret_cast<const float4*>(&s_x[k]);
        float wa0 = W1[(k + 0) * H0_ + n], wb0 = W1[(CIN + k + 0) * H0_ + n];
        float wa1 = W1[(k + 1) * H0_ + n], wb1 = W1[(CIN + k + 1) * H0_ + n];
        float wa2 = W1[(k + 2) * H0_ + n], wb2 = W1[(CIN + k + 2) * H0_ + n];
        float wa3 = W1[(k + 3) * H0_ + n], wb3 = W1[(CIN + k + 3) * H0_ + n];
        accP = fmaf(xv.x, wa0 - wb0, accP);  accQ = fmaf(xv.x, wb0, accQ);
        accP = fmaf(xv.y, wa1 - wb1, accP);  accQ = fmaf(xv.y, wb1, accQ);
        accP = fmaf(xv.z, wa2 - wb2, accP);  accQ = fmaf(xv.z, wb2, accQ);
        accP = fmaf(xv.w, wa3 - wb3, accP);  accQ = fmaf(xv.w, wb3, accQ);
    }
    P[bi * H0_ + n] = accP;
    Q[bi * H0_ + n] = accQ;
}

// ---------------------------------------------------------------------------
// EdgeConvE main, MFMA version. Block = node (b,i); 4 waves, each owns a
// 16-edge M-tile per 64-edge pass and all 128 output neurons (8 N-tiles).
// GEMM1: A = e_ij (fp32->bf16 straight from global), single K=32 step.
// Epilogue1: +P[i]+Q[j], relu, bf16 -> wave-private LDS rows (A-layout).
// GEMM2: K=128 in 4 steps, W2T fragments persistent in registers (128 VGPRs).
// Epilogue2: per-column max over edge rows; bias+relu applied after the max
// (bias is per-column; pads duplicate a real edge -> harmless for max).
// No __syncthreads in the pass loop (h1 rows are wave-private).
// ---------------------------------------------------------------------------
__global__ __launch_bounds__(256) void conv_mfma_k(
    const int* __restrict__ adj, const float* __restrict__ e,
    const float* __restrict__ P, const float* __restrict__ Q,
    const short* __restrict__ W1cT, const short* __restrict__ W2T,
    const float* __restrict__ b2, float* __restrict__ out)
{
    const int bi   = blockIdx.x;           // b*V + i
    const int b    = bi >> 8;
    const int tid  = threadIdx.x;
    const int w    = tid >> 6;
    const int lane = tid & 63;
    const int l15  = lane & 15;
    const int quad = lane >> 4;

    __shared__ int s_list[V_];
    __shared__ int s_cnt;
    __shared__ __align__(16) short s_h1[64][136];   // 272 B stride: 16B-aligned, ~2-way banks
    __shared__ float s_m[4][H0_];

    if (tid == 0) s_cnt = 0;
    __syncthreads();
    if (adj[bi * V_ + tid] > 0) { int p = atomicAdd(&s_cnt, 1); s_list[p] = tid; }
    __syncthreads();
    const int cnt = s_cnt;
    if (cnt == 0) { if (tid < H0_) out[bi * H0_ + tid] = 0.f; return; }

    // persistent B-fragments for GEMM2: lane -> row n = nt*16+l15, k = quad*8..+7
    bf16x8 B2[8][4];
    #pragma unroll
    for (int nt = 0; nt < 8; ++nt) {
        #pragma unroll
        for (int kk = 0; kk < 4; ++kk)
            B2[nt][kk] = *(const bf16x8*)(W2T + (nt * 16 + l15) * H0_ + kk * 32 + quad * 8);
    }
    float Pp[8], bb[8];
    #pragma unroll
    for (int nt = 0; nt < 8; ++nt) {
        Pp[nt] = P[bi * H0_ + nt * 16 + l15];
        bb[nt] = b2[nt * 16 + l15];
    }
    float vmax[8];
    #pragma unroll
    for (int nt = 0; nt < 8; ++nt) vmax[nt] = 0.f;

    const int row0 = w * 16;

    for (int t0 = 0; t0 < cnt; t0 += 64) {
        const int tb = t0 + row0;

        // A-fragment for GEMM1 straight from e: A[m=l15][k=quad*8+j]
        int ta = tb + l15; if (ta >= cnt) ta = cnt - 1;
        const int ja = s_list[ta];
        const float* er = e + (bi * V_ + ja) * C2_ + quad * 8;
        float4 e0 = *(const float4*)(er);
        float4 e1 = *(const float4*)(er + 4);
        bf16x8 A1;
        A1[0] = f2bf(e0.x); A1[1] = f2bf(e0.y); A1[2] = f2bf(e0.z); A1[3] = f2bf(e0.w);
        A1[4] = f2bf(e1.x); A1[5] = f2bf(e1.y); A1[6] = f2bf(e1.z); A1[7] = f2bf(e1.w);

        // GEMM1: e @ W1c (K=32, one MFMA per N-tile; B1 from L1-resident global)
        f32x4 acc[8];
        #pragma unroll
        for (int nt = 0; nt < 8; ++nt) {
            bf16x8 B1 = *(const bf16x8*)(W1cT + (nt * 16 + l15) * C2_ + quad * 8);
            f32x4 z = {0.f, 0.f, 0.f, 0.f};
            acc[nt] = __builtin_amdgcn_mfma_f32_16x16x32_bf16(A1, B1, z, 0, 0, 0);
        }

        // epilogue 1: + P[i] + Q[j], relu, bf16 -> LDS (rows = edge slots)
        #pragma unroll
        for (int r = 0; r < 4; ++r) {
            int t = tb + quad * 4 + r; if (t >= cnt) t = cnt - 1;
            const float* Qr = Q + (b * V_ + s_list[t]) * H0_ + l15;
            short* dst = &s_h1[row0 + quad * 4 + r][l15];
            #pragma unroll
            for (int nt = 0; nt < 8; ++nt) {
                float v = acc[nt][r] + Pp[nt] + Qr[nt * 16];
                dst[nt * 16] = f2bf(fmaxf(v, 0.f));
            }
        }

        // GEMM2: h1 @ W2 (wave-private rows -> no barrier; B2 in registers)
        f32x4 acc2[8];
        #pragma unroll
        for (int nt = 0; nt < 8; ++nt) { f32x4 z = {0.f,0.f,0.f,0.f}; acc2[nt] = z; }
        #pragma unroll
        for (int kk = 0; kk < 4; ++kk) {
            bf16x8 A2 = *(const bf16x8*)(&s_h1[row0 + l15][kk * 32 + quad * 8]);
            #pragma unroll
            for (int nt = 0; nt < 8; ++nt)
                acc2[nt] = __builtin_amdgcn_mfma_f32_16x16x32_bf16(A2, B2[nt][kk], acc2[nt], 0, 0, 0);
        }

        // epilogue 2: column max over the wave's 16 edge rows
        #pragma unroll
        for (int nt = 0; nt < 8; ++nt) {
            float m = fmaxf(fmaxf(acc2[nt][0], acc2[nt][1]),
                            fmaxf(acc2[nt][2], acc2[nt][3]));
            vmax[nt] = fmaxf(vmax[nt], fmaxf(m + bb[nt], 0.f));
        }
    }

    // cross-quad (rows) then cross-wave max
    #pragma unroll
    for (int nt = 0; nt < 8; ++nt) {
        float p = vmax[nt];
        p = fmaxf(p, __shfl_xor(p, 16, 64));
        p = fmaxf(p, __shfl_xor(p, 32, 64));
        if (quad == 0) s_m[w][nt * 16 + l15] = p;
    }
    __syncthreads();
    if (tid < H0_) {
        float m = fmaxf(fmaxf(s_m[0][tid], s_m[1][tid]),
                        fmaxf(s_m[2][tid], s_m[3][tid]));
        out[bi * H0_ + tid] = m;     // isolated node handled by early exit
    }
}

// ---------------------------------------------------------------------------
// Pair hoist (fp32, unchanged): Ai = x2@W3[H0:]+b3, Aj = x2@W3[:H0]
// ---------------------------------------------------------------------------
__global__ __launch_bounds__(256) void pair_pre_k(
    const float* __restrict__ x2, const float* __restrict__ W3,
    const float* __restrict__ b3, float* __restrict__ Ai, float* __restrict__ Aj)
{
    const int bi = blockIdx.x, n = threadIdx.x;
    __shared__ __align__(16) float s_x[H0_];
    if (n < H0_) s_x[n] = x2[bi * H0_ + n];
    __syncthreads();
    float aI = b3[n], aJ = 0.f;
    #pragma unroll 4
    for (int k = 0; k < H0_; k += 4) {
        float4 xv = *reinterpret_cast<const float4*>(&s_x[k]);
        aJ = fmaf(xv.x, W3[(k + 0) * H2_ + n], aJ);
        aJ = fmaf(xv.y, W3[(k + 1) * H2_ + n], aJ);
        aJ = fmaf(xv.z, W3[(k + 2) * H2_ + n], aJ);
        aJ = fmaf(xv.w, W3[(k + 3) * H2_ + n], aJ);
        aI = fmaf(xv.x, W3[(H0_ + k + 0) * H2_ + n], aI);
        aI = fmaf(xv.y, W3[(H0_ + k + 1) * H2_ + n], aI);
        aI = fmaf(xv.z, W3[(H0_ + k + 2) * H2_ + n], aI);
        aI = fmaf(xv.w, W3[(H0_ + k + 3) * H2_ + n], aI);
    }
    Ai[bi * H2_ + n] = aI;
    Aj[bi * H2_ + n] = aJ;
}

// ---------------------------------------------------------------------------
// Pair output v2: block = (b, 4 consecutive i); wave = one i. Lane (jj,c):
// 4 j's per step x 16 channels per lane; 4 shuffles per z. Cuts Aj traffic
// and shuffle count 4x vs R2.
// ---------------------------------------------------------------------------
__global__ __launch_bounds__(256) void pair_out_k(
    const float* __restrict__ Ai, const float* __restrict__ Aj,
    const float* __restrict__ Wo, const float* __restrict__ bo,
    float* __restrict__ out)
{
    const int blk  = blockIdx.x;                       // 256 blocks
    const int b    = blk >> 6;
    const int i    = ((blk & 63) << 2) + (threadIdx.x >> 6);
    const int lane = threadIdx.x & 63;
    const int jj   = lane >> 4;
    const int c    = lane & 15;

    const float* ai = Ai + (b * V_ + i) * H2_ + c * 16;
    float4 a0 = *(const float4*)(ai);
    float4 a1 = *(const float4*)(ai + 4);
    float4 a2 = *(const float4*)(ai + 8);
    float4 a3 = *(const float4*)(ai + 12);
    const float* wo = Wo + c * 16;
    float4 w0 = *(const float4*)(wo);
    float4 w1 = *(const float4*)(wo + 4);
    float4 w2 = *(const float4*)(wo + 8);
    float4 w3 = *(const float4*)(wo + 12);
    const float bo0 = bo[0];

    for (int j0 = 0; j0 < V_; j0 += 4) {
        const int j = j0 + jj;
        const float* aj = Aj + (b * V_ + j) * H2_ + c * 16;
        float4 q0 = *(const float4*)(aj);
        float4 q1 = *(const float4*)(aj + 4);
        float4 q2 = *(const float4*)(aj + 8);
        float4 q3 = *(const float4*)(aj + 12);
        float p;
        p = fmaxf(a0.x + q0.x, 0.f) * w0.x;
        p = fmaf(fmaxf(a0.y + q0.y, 0.f), w0.y, p);
        p = fmaf(fmaxf(a0.z + q0.z, 0.f), w0.z, p);
        p = fmaf(fmaxf(a0.w + q0.w, 0.f), w0.w, p);
        p = fmaf(fmaxf(a1.x + q1.x, 0.f), w1.x, p);
        p = fmaf(fmaxf(a1.y + q1.y, 0.f), w1.y, p);
        p = fmaf(fmaxf(a1.z + q1.z, 0.f), w1.z, p);
        p = fmaf(fmaxf(a1.w + q1.w, 0.f), w1.w, p);
        p = fmaf(fmaxf(a2.x + q2.x, 0.f), w2.x, p);
        p = fmaf(fmaxf(a2.y + q2.y, 0.f), w2.y, p);
        p = fmaf(fmaxf(a2.z + q2.z, 0.f), w2.z, p);
        p = fmaf(fmaxf(a2.w + q2.w, 0.f), w2.w, p);
        p = fmaf(fmaxf(a3.x + q3.x, 0.f), w3.x, p);
        p = fmaf(fmaxf(a3.y + q3.y, 0.f), w3.y, p);
        p = fmaf(fmaxf(a3.z + q3.z, 0.f), w3.z, p);
        p = fmaf(fmaxf(a3.w + q3.w, 0.f), w3.w, p);
        #pragma unroll
        for (int off = 1; off < 16; off <<= 1)
            p += __shfl_xor(p, off, 64);               // stays within jj group
        if (c == 0)
            out[(b * V_ + i) * V_ + j] = 1.f / (1.f + __builtin_expf(-(p + bo0)));
    }
}

// ---------------------------------------------------------------------------
extern "C" void kernel_launch(void* const* d_in, const int* in_sizes, int n_in,
                              void* d_out, int out_size, void* d_ws, size_t ws_size,
                              hipStream_t stream) {
    const int*   adj   = (const int*)  d_in[0];
    const float* xf    = (const float*)d_in[1];
    const float* ea    = (const float*)d_in[2];
    const float* ec1W1 = (const float*)d_in[3];
    const float* ec1b1 = (const float*)d_in[4];
    const float* ec1W2 = (const float*)d_in[5];
    const float* ec1b2 = (const float*)d_in[6];
    const float* ec2W1 = (const float*)d_in[7];
    const float* ec2b1 = (const float*)d_in[8];
    const float* ec2W2 = (const float*)d_in[9];
    const float* ec2b2 = (const float*)d_in[10];
    const float* h3W   = (const float*)d_in[11];
    const float* h3b   = (const float*)d_in[12];
    const float* oW    = (const float*)d_in[13];
    const float* ob    = (const float*)d_in[14];
    float* out = (float*)d_out;

    const int NV = B_ * V_;                    // 1024 nodes
    float* x1 = (float*)d_ws;                  // NV*H0
    float* x2 = x1 + NV * H0_;                 // NV*H0
    float* R  = x2 + NV * H0_;                 // reuse region (524288 floats)
    float* P  = R;                             // NV*H0
    float* Q  = R + NV * H0_;                  // NV*H0
    float* Ai = R;                             // NV*H2 (P/Q dead by then)
    float* Aj = R + NV * H2_;                  // NV*H2
    short* wsW = (short*)(R + 2 * NV * H2_);   // 40960 bf16 weights
    short* W1cT1 = wsW;
    short* W2T1  = wsW + 4096;
    short* W1cT2 = wsW + 20480;
    short* W2T2  = wsW + 24576;

    prep_k<<<160, 256, 0, stream>>>(ec1W1 + 2 * C1_ * H0_, ec1W2,
                                    ec2W1 + 2 * H0_ * H0_, ec2W2, wsW);
    // conv1
    node_pre_k<C1_><<<NV, 128, 0, stream>>>(xf, ec1W1, ec1b1, P, Q);
    conv_mfma_k<<<NV, 256, 0, stream>>>(adj, ea, P, Q, W1cT1, W2T1, ec1b2, x1);
    // conv2
    node_pre_k<H0_><<<NV, 128, 0, stream>>>(x1, ec2W1, ec2b1, P, Q);
    conv_mfma_k<<<NV, 256, 0, stream>>>(adj, ea, P, Q, W1cT2, W2T2, ec2b2, x2);
    // pair scoring
    pair_pre_k<<<NV, 256, 0, stream>>>(x2, h3W, h3b, Ai, Aj);
    pair_out_k<<<B_ * V_ / 4, 256, 0, stream>>>(Ai, Aj, oW, ob, out);
}